// Round 9
// baseline (188.829 us; speedup 1.0000x reference)
//
#include <hip/hip_runtime.h>
#include <hip/hip_bf16.h>

// Problem constants
#define NT      32      // time steps
#define FEAT    128     // in/out features per step
#define TRIB    8       // band width in blocks
#define BATCH   8192
#define INSIZE  (NT*FEAT)   // 4096
#define OUTCOLS (NT*FEAT)   // 4096

typedef __bf16 bf16;
typedef __bf16 bf16x4 __attribute__((ext_vector_type(4)));
typedef __bf16 bf16x8 __attribute__((ext_vector_type(8)));
typedef float  f32x4  __attribute__((ext_vector_type(4)));

__host__ __device__ __forceinline__ int nb_of(int i){ return i < TRIB ? i + 1 : TRIB; }
__host__ __device__ __forceinline__ int lo_of(int i){ int l = i - TRIB + 1; return l > 0 ? l : 0; }
__host__ __device__ __forceinline__ long off_of(int i){
  long sum = (i <= TRIB) ? (long)i*(i+1)/2 : (long)(TRIB*(TRIB+1)/2) + (long)(i - TRIB)*TRIB;
  return sum * (long)(FEAT*FEAT);
}

// ---------------- conversion kernels ----------------

__global__ void cvt_x_kernel(const float* __restrict__ x, bf16* __restrict__ xb, long n4){
  long idx = (long)blockIdx.x * blockDim.x + threadIdx.x;
  long stride = (long)gridDim.x * blockDim.x;
  const f32x4* src = (const f32x4*)x;
  bf16x4* dst = (bf16x4*)xb;
  for (long i = idx; i < n4; i += stride){
    f32x4 v = src[i];
    bf16x4 o;
    o.x = (bf16)v.x; o.y = (bf16)v.y; o.z = (bf16)v.z; o.w = (bf16)v.w;
    dst[i] = o;
  }
}

__global__ void cvt_w_kernel(const float* __restrict__ w, bf16* __restrict__ wp){
  int i = blockIdx.x;
  int n = blockIdx.y;
  int ktl = nb_of(i) * FEAT;
  int lo  = lo_of(i) * FEAT;
  long src = (long)(i*FEAT + n) * INSIZE + lo;
  long dst = off_of(i) + (long)n * ktl;
  for (int e = threadIdx.x * 4; e < ktl; e += blockDim.x * 4){
    f32x4 v = *(const f32x4*)(w + src + e);
    bf16x4 o;
    o.x = (bf16)v.x; o.y = (bf16)v.y; o.z = (bf16)v.z; o.w = (bf16)v.w;
    *(bf16x4*)(wp + dst + e) = o;
  }
}

// -------- banded GEMM R9: A direct-from-L2 to regs, B-only in LDS ----------
// BM=256, BN=128, BK=64. 256 threads = 4 waves (2M x 2N), wave tile 128x64.
// A fragments (16 rows x 64B = full cache lines) are loaded DIRECTLY from
// global (L2-resident x slice) into registers, double-buffered per K32-half
// (A0/A1, 8 frags each). LDS holds only B: 2 stages x 16 KiB = 32 KiB ->
// 2 independent blocks/CU (cross-block drift overlap). All VMEM is inline-asm
// with hand-counted vmcnt (issue order per wave is fixed by volatile asm):
//   entering tile t: outstanding = A0=A(t,k0)[8]
//   s1: issue A1=A(t,k1)[+8=16]   s2: if pf B-dma(t+1)[+4=20]
//   s3: ds_read Bk0 x4            s4: vmcnt(pf?12:8) -> A0 landed; lgkm(0)
//   s5: MFMA k0 x32               s6: ds_read Bk1 x4; vmcnt(pf?4:0) -> A1 landed
//   s7: if pf issue A0=A(t+1,k0)[+8]   lgkm(0)
//   s8: MFMA k1 x32               s9: if pf vmcnt(8) -> B landed; barrier
// B LDS tile [128][64] uses the proven slot-XOR swizzle (conflict-free).

#define BM 256
#define BN 128
#define BK 64
#define B_ELEMS (BN*BK)          // 8192 elems = 16 KiB per stage
#define B_BYTES (B_ELEMS*2)

__device__ __forceinline__ void gload16(const void* g, void* l){
  __builtin_amdgcn_global_load_lds(
      (__attribute__((address_space(1))) unsigned int*)(unsigned long long)g,
      (__attribute__((address_space(3))) unsigned int*)l,
      16, 0, 0);
}

__device__ __forceinline__ unsigned lds_addr(void* p){
  return (unsigned)(unsigned long long)(__attribute__((address_space(3))) void*)p;
}

__device__ __forceinline__ bf16x8 ds_read16(unsigned addr){
  bf16x8 r;
  asm volatile("ds_read_b128 %0, %1" : "=&v"(r) : "v"(addr));
  return r;
}

__device__ __forceinline__ bf16x8 gload16r(const bf16* p){
  bf16x8 r;
  asm volatile("global_load_dwordx4 %0, %1, off" : "=&v"(r) : "v"(p));
  return r;
}

#define MFMA32(AARR, BB0, BB1, BB2, BB3)                                                   \
  _Pragma("unroll")                                                                         \
  for (int mi = 0; mi < 8; ++mi){                                                           \
    acc[mi][0] = __builtin_amdgcn_mfma_f32_16x16x32_bf16(AARR[mi], BB0, acc[mi][0],0,0,0);  \
    acc[mi][1] = __builtin_amdgcn_mfma_f32_16x16x32_bf16(AARR[mi], BB1, acc[mi][1],0,0,0);  \
    acc[mi][2] = __builtin_amdgcn_mfma_f32_16x16x32_bf16(AARR[mi], BB2, acc[mi][2],0,0,0);  \
    acc[mi][3] = __builtin_amdgcn_mfma_f32_16x16x32_bf16(AARR[mi], BB3, acc[mi][3],0,0,0);  \
  }

__global__ __launch_bounds__(256, 2)
void gemm_band_kernel(const bf16* __restrict__ xb, const bf16* __restrict__ wp,
                      const float* __restrict__ bias, float* __restrict__ out){
  __shared__ __align__(16) bf16 lds[2 * B_ELEMS];   // 32 KiB (B only)

  const int bid = blockIdx.x;
  const int mt  = bid & 31;            // fast dim: m-tile
  const int i   = 31 - (bid >> 5);     // slow dim, descending (LPT)
  const int m0  = mt * BM;
  const int nbK = nb_of(i);
  const int ntiles = nbK * (FEAT / BK);    // 2..16 K64-tiles
  const int lo  = lo_of(i) * FEAT;
  const int Kt  = nbK * FEAT;
  const long wpo = off_of(i);

  const int tid  = threadIdx.x;
  const int lane = tid & 63;
  const int wid  = tid >> 6;           // 0..3
  const int wr   = wid >> 1;           // 0..1 -> 128-row M strip
  const int wc   = wid & 1;            // 0..1 -> 64-col N strip
  const int fr   = lane & 15;
  const int ks   = lane >> 4;          // 0..3 k-slot (8 bf16)

  const unsigned ldsBase = lds_addr((void*)lds);

  // -------- B LDS read offsets (stage-relative, slot-XOR swizzled) ---------
  unsigned offB0[4], offB1[4];
  {
    const unsigned q0 = (unsigned)(ks ^ (fr & 7));
    #pragma unroll
    for (int ni = 0; ni < 4; ++ni){
      const unsigned rb = (unsigned)(wc*64 + ni*16 + fr) * 128u;
      offB0[ni] = rb + q0*16u;
      offB1[ni] = rb + (q0^4u)*16u;
    }
  }

  // -------- B staging: pre-swizzled global source, linear LDS dest ---------
  const bf16* srcB[4];
  int dstB[4];
  {
    const int sb = (tid & 7) ^ ((tid >> 3) & 7);
    #pragma unroll
    for (int j = 0; j < 4; ++j){
      const int r = j*32 + (tid >> 3);           // 0..127
      srcB[j] = wp + wpo + (long)r * Kt + sb*8;
      dstB[j] = (j*256 + wid*64) * 8;            // wave-uniform (+lane*16B by HW)
    }
  }

  // -------- A direct: per-lane base; frag (mi,kh,t) at +mi*16*INSIZE + t*64 + kh*32
  const bf16* abase = xb + (long)(m0 + wr*128 + fr) * INSIZE + lo + ks*8;

  bf16x8 A0[8], A1[8];

  // -------- prologue: A(0,k0) -> A0; B(0) -> buf0 --------------------------
  #pragma unroll
  for (int mi = 0; mi < 8; ++mi) A0[mi] = gload16r(abase + mi*(16*INSIZE));
  #pragma unroll
  for (int j = 0; j < 4; ++j) gload16(srcB[j], lds + dstB[j]);
  asm volatile("s_waitcnt vmcnt(0)" ::: "memory");
  __builtin_amdgcn_s_barrier();
  asm volatile("" ::: "memory");

  f32x4 acc[8][4] = {};

  for (int t = 0; t < ntiles; ++t){
    const unsigned cB = ldsBase + (unsigned)(t & 1) * B_BYTES;
    bf16* pb = lds + ((t & 1) ^ 1) * B_ELEMS;
    const bool pf = (t + 1 < ntiles);
    const bf16* at = abase + t*BK;

    // s1: issue A(t,k1)
    #pragma unroll
    for (int mi = 0; mi < 8; ++mi) A1[mi] = gload16r(at + mi*(16*INSIZE) + 32);
    // s2: B-dma(t+1) into the other stage
    if (pf){
      #pragma unroll
      for (int j = 0; j < 4; ++j) gload16(srcB[j] + (t+1)*BK, pb + dstB[j]);
    }
    // s3: B k0 fragments
    bf16x8 b0 = ds_read16(cB + offB0[0]);
    bf16x8 b1 = ds_read16(cB + offB0[1]);
    bf16x8 b2 = ds_read16(cB + offB0[2]);
    bf16x8 b3 = ds_read16(cB + offB0[3]);
    // s4: A0 landed (retire 8 oldest), B k0 read
    if (pf) asm volatile("s_waitcnt vmcnt(12) lgkmcnt(0)" ::: "memory");
    else    asm volatile("s_waitcnt vmcnt(8) lgkmcnt(0)" ::: "memory");
    __builtin_amdgcn_sched_barrier(0);
    // s5: MFMA k0
    __builtin_amdgcn_s_setprio(1);
    MFMA32(A0, b0, b1, b2, b3)
    __builtin_amdgcn_s_setprio(0);
    // s6: B k1 fragments; A1 landed
    bf16x8 c0 = ds_read16(cB + offB1[0]);
    bf16x8 c1 = ds_read16(cB + offB1[1]);
    bf16x8 c2 = ds_read16(cB + offB1[2]);
    bf16x8 c3 = ds_read16(cB + offB1[3]);
    if (pf) asm volatile("s_waitcnt vmcnt(4)" ::: "memory");
    else    asm volatile("s_waitcnt vmcnt(0)" ::: "memory");
    __builtin_amdgcn_sched_barrier(0);
    // s7: issue A(t+1,k0) (stays in flight across the barrier - counted)
    if (pf){
      const bf16* an = abase + (t+1)*BK;
      #pragma unroll
      for (int mi = 0; mi < 8; ++mi) A0[mi] = gload16r(an + mi*(16*INSIZE));
    }
    asm volatile("s_waitcnt lgkmcnt(0)" ::: "memory");
    __builtin_amdgcn_sched_barrier(0);
    // s8: MFMA k1
    __builtin_amdgcn_s_setprio(1);
    MFMA32(A1, c0, c1, c2, c3)
    __builtin_amdgcn_s_setprio(0);
    // s9: B-dma(t+1) landed (retire 4 oldest, keep A(t+1,k0) in flight)
    if (pf){
      asm volatile("s_waitcnt vmcnt(8)" ::: "memory");
      __builtin_amdgcn_s_barrier();
      asm volatile("" ::: "memory");
    }
  }

  // -------- epilogue: C/D layout col = lane&15, row = (lane>>4)*4 + reg ----
  #pragma unroll
  for (int ni = 0; ni < 4; ++ni){
    const int gcol = i*FEAT + wc*64 + ni*16 + fr;
    const float bv = bias[gcol];
    #pragma unroll
    for (int mi = 0; mi < 8; ++mi){
      const int rbase = m0 + wr*128 + mi*16 + ks*4;
      #pragma unroll
      for (int r2 = 0; r2 < 4; ++r2)
        out[(long)(rbase + r2) * OUTCOLS + gcol] = acc[mi][ni][r2] + bv;
    }
  }
}

// ---------------- fallback (tiny ws): naive fp32, band-limited ----------------
__global__ void naive_kernel(const float* __restrict__ x, const float* __restrict__ w,
                             const float* __restrict__ bias, float* __restrict__ out){
  long idx = (long)blockIdx.x * blockDim.x + threadIdx.x;
  int o = (int)(idx & (OUTCOLS - 1));
  int b = (int)(idx >> 12);
  int i = o >> 7;
  int lo = lo_of(i) * FEAT, hi = (i + 1) * FEAT;
  const float* xr = x + (long)b * INSIZE;
  const float* wr = w + (long)o * INSIZE;
  float s = bias[o];
  for (int k = lo; k < hi; k += 4){
    f32x4 xv = *(const f32x4*)(xr + k);
    f32x4 wv = *(const f32x4*)(wr + k);
    s += xv.x*wv.x + xv.y*wv.y + xv.z*wv.z + xv.w*wv.w;
  }
  out[idx] = s;
}

// ---------------- launch ----------------
extern "C" void kernel_launch(void* const* d_in, const int* in_sizes, int n_in,
                              void* d_out, int out_size, void* d_ws, size_t ws_size,
                              hipStream_t stream) {
  const float* x    = (const float*)d_in[0];
  const float* w    = (const float*)d_in[1];
  const float* bias = (const float*)d_in[2];
  float* out = (float*)d_out;

  const size_t x_bytes = (size_t)BATCH * INSIZE * sizeof(bf16);        // 64 MiB
  const size_t w_bytes = (size_t)228 * FEAT * FEAT * sizeof(bf16);     // ~7.5 MiB
  if (ws_size >= x_bytes + w_bytes){
    bf16* xb = (bf16*)d_ws;
    bf16* wp = (bf16*)((char*)d_ws + x_bytes);
    cvt_x_kernel<<<2048, 256, 0, stream>>>(x, xb, (long)BATCH * INSIZE / 4);
    cvt_w_kernel<<<dim3(NT, FEAT), 256, 0, stream>>>(w, wp);
    gemm_band_kernel<<<dim3(NT * (BATCH/BM)), 256, 0, stream>>>(xb, wp, bias, out);
  } else {
    naive_kernel<<<(long)BATCH * OUTCOLS / 256, 256, 0, stream>>>(x, w, bias, out);
  }
}

// Round 10
// 135.987 us; speedup vs baseline: 1.3886x; 1.3886x over previous
//
#include <hip/hip_runtime.h>
#include <hip/hip_bf16.h>

// Problem constants
#define NT      32      // time steps
#define FEAT    128     // in/out features per step
#define TRIB    8       // band width in blocks
#define BATCH   8192
#define INSIZE  (NT*FEAT)   // 4096
#define OUTCOLS (NT*FEAT)   // 4096

typedef __bf16 bf16;
typedef __bf16 bf16x4 __attribute__((ext_vector_type(4)));
typedef __bf16 bf16x8 __attribute__((ext_vector_type(8)));
typedef float  f32x4  __attribute__((ext_vector_type(4)));

__host__ __device__ __forceinline__ int nb_of(int i){ return i < TRIB ? i + 1 : TRIB; }
__host__ __device__ __forceinline__ int lo_of(int i){ int l = i - TRIB + 1; return l > 0 ? l : 0; }
__host__ __device__ __forceinline__ long off_of(int i){
  long sum = (i <= TRIB) ? (long)i*(i+1)/2 : (long)(TRIB*(TRIB+1)/2) + (long)(i - TRIB)*TRIB;
  return sum * (long)(FEAT*FEAT);
}

// ---------------- conversion kernels ----------------

__global__ void cvt_x_kernel(const float* __restrict__ x, bf16* __restrict__ xb, long n4){
  long idx = (long)blockIdx.x * blockDim.x + threadIdx.x;
  long stride = (long)gridDim.x * blockDim.x;
  const f32x4* src = (const f32x4*)x;
  bf16x4* dst = (bf16x4*)xb;
  for (long i = idx; i < n4; i += stride){
    f32x4 v = src[i];
    bf16x4 o;
    o.x = (bf16)v.x; o.y = (bf16)v.y; o.z = (bf16)v.z; o.w = (bf16)v.w;
    dst[i] = o;
  }
}

__global__ void cvt_w_kernel(const float* __restrict__ w, bf16* __restrict__ wp){
  int i = blockIdx.x;
  int n = blockIdx.y;
  int ktl = nb_of(i) * FEAT;
  int lo  = lo_of(i) * FEAT;
  long src = (long)(i*FEAT + n) * INSIZE + lo;
  long dst = off_of(i) + (long)n * ktl;
  for (int e = threadIdx.x * 4; e < ktl; e += blockDim.x * 4){
    f32x4 v = *(const f32x4*)(w + src + e);
    bf16x4 o;
    o.x = (bf16)v.x; o.y = (bf16)v.y; o.z = (bf16)v.z; o.w = (bf16)v.w;
    *(bf16x4*)(wp + dst + e) = o;
  }
}

// ----- banded GEMM R10: 128x64 wave tile + 2 blocks/CU + XCD-chunked grid ----
// BM=256, BN=128, BK=32. 256 threads = 4 waves (2M x 2N), wave tile 128x64
// (R5's efficient LDS-bytes/FLOP). 3-stage LDS = 72 KiB -> TWO independent
// blocks/CU (R6-proven cross-block drift overlap; ~232 regs = 2 waves/SIMD).
// Grid: 1024 blocks; XCD-chunked remap (m204-bijective, xcd = bid&7): XCD k
// owns m-tiles [4k,4k+4), sweeps i descending (LPT) with mt fast -> x sliding
// window stays in per-XCD L2/L3, cutting xb re-fetch.
// Same proven superrow XOR swizzle (SQ_LDS_BANK_CONFLICT=0 since R3), asm
// ds_read, free-run single barrier + counted vmcnt(6) per tile (R5 schedule).

#define BM 256
#define BN 128
#define BK 32
#define NSTAGE 3
#define A_ELEMS (BM*BK)              // 8192 elems = 16 KiB
#define B_ELEMS (BN*BK)              // 4096 elems =  8 KiB
#define TILE_ELEMS (A_ELEMS + B_ELEMS)   // 24 KiB/stage

__device__ __forceinline__ void gload16(const void* g, void* l){
  __builtin_amdgcn_global_load_lds(
      (__attribute__((address_space(1))) unsigned int*)(unsigned long long)g,
      (__attribute__((address_space(3))) unsigned int*)l,
      16, 0, 0);
}

__device__ __forceinline__ unsigned lds_addr(void* p){
  return (unsigned)(unsigned long long)(__attribute__((address_space(3))) void*)p;
}

__device__ __forceinline__ bf16x8 ds_read16(unsigned addr){
  bf16x8 r;
  asm volatile("ds_read_b128 %0, %1" : "=&v"(r) : "v"(addr));
  return r;
}

__global__ __launch_bounds__(256, 2)
void gemm_band_kernel(const bf16* __restrict__ xb, const bf16* __restrict__ wp,
                      const float* __restrict__ bias, float* __restrict__ out){
  __shared__ __align__(16) bf16 lds[NSTAGE * TILE_ELEMS];   // 72 KiB

  // ---- XCD-chunked remap: 1024 blocks, xcd = bid&7 (round-robin dispatch),
  //      XCD k gets chunk k = {mt in [4k,4k+4)} x {all i}, i descending, mt fast.
  const int bid = blockIdx.x;
  const int xcd = bid & 7;
  const int idx = bid >> 3;            // 0..127 within chunk
  const int i   = 31 - (idx >> 2);     // slow, descending (LPT)
  const int mt  = xcd * 4 + (idx & 3); // fast within chunk
  const int m0  = mt * BM;
  const int nbK = nb_of(i);
  const int ntiles = nbK * (FEAT / BK);    // 4..32 K32-tiles
  const int lo  = lo_of(i) * FEAT;
  const int Kt  = nbK * FEAT;
  const long wpo = off_of(i);

  const int tid  = threadIdx.x;
  const int lane = tid & 63;
  const int wid  = tid >> 6;           // 0..3
  const int wr   = wid >> 1;           // 0..1 -> 128-row M strip
  const int wc   = wid & 1;            // 0..1 -> 64-col N strip
  const int fr   = lane & 15;
  const int ks   = lane >> 4;          // 0..3 k-slot (8 bf16)

  const unsigned ldsBase = lds_addr((void*)lds);

  // -------- loop-invariant LDS read BYTE offsets (superrow-packed swizzle) --
  unsigned offA[8], offB[4];
  #pragma unroll
  for (int mi = 0; mi < 8; ++mi){
    const int row = wr*128 + mi*16 + fr;
    const int u = row >> 1;
    const int q = (((row & 1) << 2) | ks) ^ (u & 7);
    offA[mi] = (unsigned)(u*64 + q*8) * 2u;
  }
  #pragma unroll
  for (int ni = 0; ni < 4; ++ni){
    const int row = wc*64 + ni*16 + fr;
    const int u = row >> 1;
    const int q = (((row & 1) << 2) | ks) ^ (u & 7);
    offB[ni] = (unsigned)(A_ELEMS*2) + (unsigned)(u*64 + q*8) * 2u;
  }

  // -------- staging: pre-permuted global source, linear LDS dest -----------
  // A: 1024 16B-chunks/stage; thread covers c = j*256+tid, j=0..3.
  // B:  512 16B-chunks/stage; thread covers c = j*256+tid, j=0..1.
  const bf16* srcA[4];
  int dstA[4];
  #pragma unroll
  for (int j = 0; j < 4; ++j){
    const int c = j*256 + tid;
    const int u = c >> 3, qq = c & 7;
    const int s8 = qq ^ (u & 7);
    const int r  = 2*u + (s8 >> 2);
    const int sa = s8 & 3;
    srcA[j] = xb + (long)(m0 + r) * INSIZE + lo + sa*8;
    dstA[j] = (j*256 + wid*64) * 8;    // wave-uniform (+lane*16B by HW)
  }
  const bf16* srcB[2];
  int dstB[2];
  #pragma unroll
  for (int j = 0; j < 2; ++j){
    const int c = j*256 + tid;
    const int u = c >> 3, qq = c & 7;
    const int s8 = qq ^ (u & 7);
    const int r  = 2*u + (s8 >> 2);
    const int sb = s8 & 3;
    srcB[j] = wp + wpo + (long)r * Kt + sb*8;
    dstB[j] = A_ELEMS + (j*256 + wid*64) * 8;
  }

  auto stage = [&](bf16* base, int t){
    gload16(srcA[0] + t*BK, base + dstA[0]);
    gload16(srcA[1] + t*BK, base + dstA[1]);
    gload16(srcA[2] + t*BK, base + dstA[2]);
    gload16(srcA[3] + t*BK, base + dstA[3]);
    gload16(srcB[0] + t*BK, base + dstB[0]);
    gload16(srcB[1] + t*BK, base + dstB[1]);
  };

  // -------- prologue: fill stages 0,1 (ntiles >= 4 always) -----------------
  stage(lds, 0);
  stage(lds + TILE_ELEMS, 1);

  f32x4 acc[8][4] = {};

  asm volatile("s_waitcnt vmcnt(6)" ::: "memory");   // my stage-0 loads landed
  __builtin_amdgcn_s_barrier();                      // everyone's landed
  asm volatile("" ::: "memory");

  int stC = 0, stPf = 2;
  for (int t = 0; t < ntiles; ++t){
    const unsigned cA = ldsBase + (unsigned)stC * (TILE_ELEMS*2);
    bf16* pfBase = lds + stPf * TILE_ELEMS;
    const bool pf = (t + 2 < ntiles);

    // ---- issue all 12 ds_reads for tile t
    bf16x8 a0 = ds_read16(cA + offA[0]);
    bf16x8 a1 = ds_read16(cA + offA[1]);
    bf16x8 a2 = ds_read16(cA + offA[2]);
    bf16x8 a3 = ds_read16(cA + offA[3]);
    bf16x8 a4 = ds_read16(cA + offA[4]);
    bf16x8 a5 = ds_read16(cA + offA[5]);
    bf16x8 a6 = ds_read16(cA + offA[6]);
    bf16x8 a7 = ds_read16(cA + offA[7]);
    bf16x8 b0 = ds_read16(cA + offB[0]);
    bf16x8 b1 = ds_read16(cA + offB[1]);
    bf16x8 b2 = ds_read16(cA + offB[2]);
    bf16x8 b3 = ds_read16(cA + offB[3]);

    // ---- issue tile t+2 staging (writes buf t-1, safe per prev barrier)
    if (pf) stage(pfBase, t + 2);

    // ---- my reads done -> MFMA cluster (free-run, no pre-MFMA barrier)
    asm volatile("s_waitcnt lgkmcnt(0)" ::: "memory");
    __builtin_amdgcn_sched_barrier(0);
    __builtin_amdgcn_s_setprio(1);
    acc[0][0] = __builtin_amdgcn_mfma_f32_16x16x32_bf16(a0, b0, acc[0][0], 0,0,0);
    acc[0][1] = __builtin_amdgcn_mfma_f32_16x16x32_bf16(a0, b1, acc[0][1], 0,0,0);
    acc[0][2] = __builtin_amdgcn_mfma_f32_16x16x32_bf16(a0, b2, acc[0][2], 0,0,0);
    acc[0][3] = __builtin_amdgcn_mfma_f32_16x16x32_bf16(a0, b3, acc[0][3], 0,0,0);
    acc[1][0] = __builtin_amdgcn_mfma_f32_16x16x32_bf16(a1, b0, acc[1][0], 0,0,0);
    acc[1][1] = __builtin_amdgcn_mfma_f32_16x16x32_bf16(a1, b1, acc[1][1], 0,0,0);
    acc[1][2] = __builtin_amdgcn_mfma_f32_16x16x32_bf16(a1, b2, acc[1][2], 0,0,0);
    acc[1][3] = __builtin_amdgcn_mfma_f32_16x16x32_bf16(a1, b3, acc[1][3], 0,0,0);
    acc[2][0] = __builtin_amdgcn_mfma_f32_16x16x32_bf16(a2, b0, acc[2][0], 0,0,0);
    acc[2][1] = __builtin_amdgcn_mfma_f32_16x16x32_bf16(a2, b1, acc[2][1], 0,0,0);
    acc[2][2] = __builtin_amdgcn_mfma_f32_16x16x32_bf16(a2, b2, acc[2][2], 0,0,0);
    acc[2][3] = __builtin_amdgcn_mfma_f32_16x16x32_bf16(a2, b3, acc[2][3], 0,0,0);
    acc[3][0] = __builtin_amdgcn_mfma_f32_16x16x32_bf16(a3, b0, acc[3][0], 0,0,0);
    acc[3][1] = __builtin_amdgcn_mfma_f32_16x16x32_bf16(a3, b1, acc[3][1], 0,0,0);
    acc[3][2] = __builtin_amdgcn_mfma_f32_16x16x32_bf16(a3, b2, acc[3][2], 0,0,0);
    acc[3][3] = __builtin_amdgcn_mfma_f32_16x16x32_bf16(a3, b3, acc[3][3], 0,0,0);
    acc[4][0] = __builtin_amdgcn_mfma_f32_16x16x32_bf16(a4, b0, acc[4][0], 0,0,0);
    acc[4][1] = __builtin_amdgcn_mfma_f32_16x16x32_bf16(a4, b1, acc[4][1], 0,0,0);
    acc[4][2] = __builtin_amdgcn_mfma_f32_16x16x32_bf16(a4, b2, acc[4][2], 0,0,0);
    acc[4][3] = __builtin_amdgcn_mfma_f32_16x16x32_bf16(a4, b3, acc[4][3], 0,0,0);
    acc[5][0] = __builtin_amdgcn_mfma_f32_16x16x32_bf16(a5, b0, acc[5][0], 0,0,0);
    acc[5][1] = __builtin_amdgcn_mfma_f32_16x16x32_bf16(a5, b1, acc[5][1], 0,0,0);
    acc[5][2] = __builtin_amdgcn_mfma_f32_16x16x32_bf16(a5, b2, acc[5][2], 0,0,0);
    acc[5][3] = __builtin_amdgcn_mfma_f32_16x16x32_bf16(a5, b3, acc[5][3], 0,0,0);
    acc[6][0] = __builtin_amdgcn_mfma_f32_16x16x32_bf16(a6, b0, acc[6][0], 0,0,0);
    acc[6][1] = __builtin_amdgcn_mfma_f32_16x16x32_bf16(a6, b1, acc[6][1], 0,0,0);
    acc[6][2] = __builtin_amdgcn_mfma_f32_16x16x32_bf16(a6, b2, acc[6][2], 0,0,0);
    acc[6][3] = __builtin_amdgcn_mfma_f32_16x16x32_bf16(a6, b3, acc[6][3], 0,0,0);
    acc[7][0] = __builtin_amdgcn_mfma_f32_16x16x32_bf16(a7, b0, acc[7][0], 0,0,0);
    acc[7][1] = __builtin_amdgcn_mfma_f32_16x16x32_bf16(a7, b1, acc[7][1], 0,0,0);
    acc[7][2] = __builtin_amdgcn_mfma_f32_16x16x32_bf16(a7, b2, acc[7][2], 0,0,0);
    acc[7][3] = __builtin_amdgcn_mfma_f32_16x16x32_bf16(a7, b3, acc[7][3], 0,0,0);
    __builtin_amdgcn_s_setprio(0);

    // ---- single per-tile sync: my stage(t+1) retired + everyone ready
    if (t + 1 < ntiles){
      if (pf) asm volatile("s_waitcnt vmcnt(6)" ::: "memory");
      else    asm volatile("s_waitcnt vmcnt(0)" ::: "memory");
      __builtin_amdgcn_s_barrier();
      asm volatile("" ::: "memory");
    }

    stC  = (stC  == NSTAGE-1) ? 0 : stC  + 1;
    stPf = (stPf == NSTAGE-1) ? 0 : stPf + 1;
  }

  // -------- epilogue: C/D layout col = lane&15, row = (lane>>4)*4 + reg ----
  #pragma unroll
  for (int ni = 0; ni < 4; ++ni){
    const int gcol = i*FEAT + wc*64 + ni*16 + fr;
    const float bv = bias[gcol];
    #pragma unroll
    for (int mi = 0; mi < 8; ++mi){
      const int rbase = m0 + wr*128 + mi*16 + ks*4;
      #pragma unroll
      for (int r2 = 0; r2 < 4; ++r2)
        out[(long)(rbase + r2) * OUTCOLS + gcol] = acc[mi][ni][r2] + bv;
    }
  }
}

// ---------------- fallback (tiny ws): naive fp32, band-limited ----------------
__global__ void naive_kernel(const float* __restrict__ x, const float* __restrict__ w,
                             const float* __restrict__ bias, float* __restrict__ out){
  long idx = (long)blockIdx.x * blockDim.x + threadIdx.x;
  int o = (int)(idx & (OUTCOLS - 1));
  int b = (int)(idx >> 12);
  int i = o >> 7;
  int lo = lo_of(i) * FEAT, hi = (i + 1) * FEAT;
  const float* xr = x + (long)b * INSIZE;
  const float* wr = w + (long)o * INSIZE;
  float s = bias[o];
  for (int k = lo; k < hi; k += 4){
    f32x4 xv = *(const f32x4*)(xr + k);
    f32x4 wv = *(const f32x4*)(wr + k);
    s += xv.x*wv.x + xv.y*wv.y + xv.z*wv.z + xv.w*wv.w;
  }
  out[idx] = s;
}

// ---------------- launch ----------------
extern "C" void kernel_launch(void* const* d_in, const int* in_sizes, int n_in,
                              void* d_out, int out_size, void* d_ws, size_t ws_size,
                              hipStream_t stream) {
  const float* x    = (const float*)d_in[0];
  const float* w    = (const float*)d_in[1];
  const float* bias = (const float*)d_in[2];
  float* out = (float*)d_out;

  const size_t x_bytes = (size_t)BATCH * INSIZE * sizeof(bf16);        // 64 MiB
  const size_t w_bytes = (size_t)228 * FEAT * FEAT * sizeof(bf16);     // ~7.5 MiB
  if (ws_size >= x_bytes + w_bytes){
    bf16* xb = (bf16*)d_ws;
    bf16* wp = (bf16*)((char*)d_ws + x_bytes);
    cvt_x_kernel<<<2048, 256, 0, stream>>>(x, xb, (long)BATCH * INSIZE / 4);
    cvt_w_kernel<<<dim3(NT, FEAT), 256, 0, stream>>>(w, wp);
    gemm_band_kernel<<<dim3(NT * (BATCH/BM)), 256, 0, stream>>>(xb, wp, bias, out);
  } else {
    naive_kernel<<<(long)BATCH * OUTCOLS / 256, 256, 0, stream>>>(x, w, bias, out);
  }
}